// Round 8
// baseline (258.543 us; speedup 1.0000x reference)
//
#include <hip/hip_runtime.h>
#include <cstdint>
#include <cstddef>

// Problem constants
#define S_LEN  2048
#define NHEAD  16
#define HDIM   64
#define KD     1024   // D_IN == D_OUT
#define BSROWS 8192   // B * S

typedef __attribute__((ext_vector_type(4))) float          floatx4;
typedef __attribute__((ext_vector_type(8))) __bf16         bf16x8;
typedef __attribute__((ext_vector_type(8))) unsigned short ushort8v;
typedef __attribute__((ext_vector_type(4))) unsigned short ushort4v;
typedef __attribute__((ext_vector_type(4))) float          float4v;

// fp32 -> bf16 round-to-nearest-even on the bit pattern (inputs are finite)
__device__ __forceinline__ unsigned short f2bf(float f) {
  unsigned int u = __float_as_uint(f);
  u += 0x7fffu + ((u >> 16) & 1u);
  return (unsigned short)(u >> 16);
}

// fast exp2 (single v_exp_f32)
#if __has_builtin(__builtin_amdgcn_exp2f)
#define EXP2F(x) __builtin_amdgcn_exp2f(x)
#else
#define EXP2F(x) exp2f(x)
#endif

// pack two fp32 into packed bf16 (truncation; bias cancels in O/l)
__device__ __forceinline__ unsigned int pack2bf(float a, float b) {
#if __has_builtin(__builtin_amdgcn_perm)
  return __builtin_amdgcn_perm(__float_as_uint(b), __float_as_uint(a), 0x07060302);
#else
  return (__float_as_uint(a) >> 16) | (__float_as_uint(b) & 0xffff0000u);
#endif
}

// async global->LDS, 16B per lane; LDS dest is wave-uniform base + lane*16
__device__ __forceinline__ void async_cp16(const void* gsrc, void* ldst) {
  __builtin_amdgcn_global_load_lds(
      (__attribute__((address_space(1))) void*)gsrc,
      (__attribute__((address_space(3))) void*)ldst,
      16, 0, 0);
}

// ---------------------------------------------------------------------------
// Kernel 1: fp32 -> bf16 conversion of x, W_q|W_k|W_v (concat), W_o
// ---------------------------------------------------------------------------
#define XN4 2097152   // B*S*D_IN / 4
#define WN4 262144    // 1024*1024 / 4

__global__ __launch_bounds__(256) void cvt_kernel(
    const float* __restrict__ x,  const float* __restrict__ wq,
    const float* __restrict__ wk, const float* __restrict__ wv,
    const float* __restrict__ wo,
    unsigned short* __restrict__ xb, unsigned short* __restrict__ wqkvb,
    unsigned short* __restrict__ wob)
{
  const int i = blockIdx.x * 256 + threadIdx.x;
  const float* src; unsigned short* dst; int off;
  if (i < XN4) { src = x; dst = xb; off = i; }
  else {
    const int j = i - XN4;
    if (j < WN4)          { src = wq; dst = wqkvb;           off = j; }
    else if (j < 2*WN4)   { src = wk; dst = wqkvb + 4*WN4;   off = j - WN4; }
    else if (j < 3*WN4)   { src = wv; dst = wqkvb + 8*WN4;   off = j - 2*WN4; }
    else                  { src = wo; dst = wob;             off = j - 3*WN4; }
  }
  const float4v v = ((const float4v*)src)[off];
  ushort4v o;
  o.x = f2bf(v.x); o.y = f2bf(v.y); o.z = f2bf(v.z); o.w = f2bf(v.w);
  ((ushort4v*)dst)[off] = o;
}

// ---------------------------------------------------------------------------
// Kernel 2: fused QKV projection, NT bf16 GEMM [8192,1024] x [3072,1024]^T
// DISTANCE-2 async pipeline (AITER pattern): triple-buffered staging via
// global_load_lds; steady-state barrier waits only the OLDEST tile's 4 loads
// (s_waitcnt vmcnt(4)) so the next tile's loads stay in flight across the
// barrier — each load gets ~2 compute phases to land. Last iter peeled with
// vmcnt(0). XOR-swizzled staging/frag reads (R7, conflict-minimal).
// Q/K epilogue: C -> LDS (stride 130) -> coalesced 16B stores [b,h,s,hd].
// V  epilogue: C -> LDS TRANSPOSED (stride 136) -> 16B stores into Vt.
// ---------------------------------------------------------------------------
__global__ __launch_bounds__(256) void gemm_qkv(
    const unsigned short* __restrict__ A,
    const unsigned short* __restrict__ Bw,
    unsigned short* __restrict__ Qo,
    unsigned short* __restrict__ Ko,
    unsigned short* __restrict__ Vto)
{
  // 3 bufs x (As 4096 | Bs 4096) shorts = 49152 B; epilogue reuses (<=17408 sh)
  __shared__ unsigned short smem[24576];
  const int tid  = threadIdx.x;
  const int wave = tid >> 6, lane = tid & 63;
  const int quad = lane >> 4, l15 = lane & 15;
  const int wr = wave >> 1, wc = wave & 1;
  const int m0 = blockIdx.x * 128, n0 = blockIdx.y * 128;

  const int srow = lane >> 2;
  const int scol = ((lane & 3) ^ ((srow >> 1) & 3)) * 8;   // XOR-swizzled source
  const unsigned short* gA = A  + (size_t)(m0 + wave * 32 + srow) * KD + scol;
  const unsigned short* gB = Bw + (size_t)(n0 + wave * 32 + srow) * KD + scol;
  unsigned short* lA0 = smem + wave * 1024;
  unsigned short* lB0 = smem + 4096 + wave * 1024;

  const floatx4 fzero = {0.f, 0.f, 0.f, 0.f};
  floatx4 acc[4][4];
#pragma unroll
  for (int i = 0; i < 4; i++)
#pragma unroll
    for (int j = 0; j < 4; j++) acc[i][j] = fzero;

  // prologue: stage K-tiles 0 and 1 -> bufs 0,1
#pragma unroll
  for (int t = 0; t < 2; t++) {
    async_cp16(gA + t * 32,                   lA0 + t * 8192);
    async_cp16(gA + t * 32 + (size_t)16 * KD, lA0 + t * 8192 + 512);
    async_cp16(gB + t * 32,                   lB0 + t * 8192);
    async_cp16(gB + t * 32 + (size_t)16 * KD, lB0 + t * 8192 + 512);
  }
  const int lsw = (l15 >> 1) & 3;    // loop-invariant frag-read swizzle

  auto compute = [&](int it) {
    const unsigned short* As = smem + (it % 3) * 8192;
    const unsigned short* Bs = As + 4096;
    bf16x8 af[4], bfrag[4];
#pragma unroll
    for (int i = 0; i < 4; i++)
      af[i] = *(const bf16x8*)&As[(wr * 64 + i * 16 + l15) * 32 + (quad ^ lsw) * 8];
#pragma unroll
    for (int j = 0; j < 4; j++)
      bfrag[j] = *(const bf16x8*)&Bs[(wc * 64 + j * 16 + l15) * 32 + (quad ^ lsw) * 8];
#pragma unroll
    for (int i = 0; i < 4; i++)
#pragma unroll
      for (int j = 0; j < 4; j++)
        acc[i][j] = __builtin_amdgcn_mfma_f32_16x16x32_bf16(af[i], bfrag[j], acc[i][j], 0, 0, 0);
  };

  for (int it = 0; it < 31; it++) {
    // wait ONLY the oldest tile's 4 loads (4 newer stay in flight), then barrier
    asm volatile("s_waitcnt vmcnt(4) lgkmcnt(0)\n\ts_barrier" ::: "memory");
    if (it + 2 < 32) {               // prefetch K-tile it+2 -> buf (it+2)%3
      const int nb = (it + 2) % 3;
      const int ko = (it + 2) * 32;
      async_cp16(gA + ko,                   lA0 + nb * 8192);
      async_cp16(gA + ko + (size_t)16 * KD, lA0 + nb * 8192 + 512);
      async_cp16(gB + ko,                   lB0 + nb * 8192);
      async_cp16(gB + ko + (size_t)16 * KD, lB0 + nb * 8192 + 512);
    }
    compute(it);
  }
  asm volatile("s_waitcnt vmcnt(0) lgkmcnt(0)\n\ts_barrier" ::: "memory");
  compute(31);

  const int which = n0 >> 10;                     // 0:Q 1:K 2:V
  const int h0 = (n0 & 1023) >> 6;                // first head of this n-block
  const int b = m0 >> 11, sl = m0 & 2047;

  if (which < 2) {
    unsigned short* dst = which ? Ko : Qo;
    const float scale = which ? 1.0f : 0.18033688011112042f;  // Q: 0.125*log2(e)
    __syncthreads();                              // staging dead -> reuse as Ct[s][n]
    const int crow = wr * 64 + quad * 4;
    const int ccol = wc * 64 + l15;
#pragma unroll
    for (int i = 0; i < 4; i++)
#pragma unroll
      for (int j = 0; j < 4; j++)
#pragma unroll
        for (int r = 0; r < 4; r++)
          smem[(crow + i * 16 + r) * 130 + ccol + j * 16] = f2bf(acc[i][j][r] * scale);
    __syncthreads();
#pragma unroll
    for (int t = 0; t < 8; t++) {
      const int c   = t * 256 + tid;
      const int hd8 = (c & 7) * 8;
      const int hh  = (c >> 3) & 1;
      const int s   = c >> 4;
      const ushort8v val = *(const ushort8v*)&smem[s * 130 + hh * 64 + hd8];
      *(ushort8v*)&dst[((size_t)((b * NHEAD + h0 + hh) * S_LEN + sl + s)) * HDIM + hd8] = val;
    }
  } else {
    // V: stage TRANSPOSED Ct[n][s] (stride 136), then Vt[b,h,hd,s] stores.
    __syncthreads();
    const int crow = wr * 64 + quad * 4;          // s_local
    const int ccol = wc * 64 + l15;               // n_local
#pragma unroll
    for (int i = 0; i < 4; i++)
#pragma unroll
      for (int j = 0; j < 4; j++) {
        ushort4v t4;
#pragma unroll
        for (int r = 0; r < 4; r++) t4[r] = f2bf(acc[i][j][r]);
        *(ushort4v*)&smem[(ccol + j * 16) * 136 + crow + i * 16] = t4;
      }
    __syncthreads();
#pragma unroll
    for (int t = 0; t < 8; t++) {
      const int c  = t * 256 + tid;
      const int nl = c >> 4, sc = (c & 15) * 8;
      const ushort8v val = *(const ushort8v*)&smem[nl * 136 + sc];
      *(ushort8v*)&Vto[((size_t)((b * NHEAD + h0 + (nl >> 6)) * HDIM + (nl & 63))) * S_LEN + sl + sc] = val;
    }
  }
}

// ---------------------------------------------------------------------------
// Kernel 3: causal flash attention, S^T formulation, DISTANCE-2 pipeline.
// 512 thr = 8 waves; wave owns 32 q (2 subtiles of 16). Q tile = 256 rows.
// Triple-buffered K/V staging (global_load_lds, XOR source swizzle); steady
// barrier waits only the oldest tile's 2 loads (vmcnt(2)); last tile peeled
// with vmcnt(0). P buffer: stride-64 rows with XOR-chunk swizzle
// (chunk ^= q&7) -> writes 2-way (free), PV B-frag reads single aligned
// conflict-free ds_read_b128. bh-major grid for XCD L2 residency.
// LDS 81920 B = 3x16384 (K/V) + 32768 (P) -> exactly 2 blocks/CU.
// ---------------------------------------------------------------------------
__global__ __launch_bounds__(512, 4) void attn_kernel(
    const unsigned short* __restrict__ Qg_,
    const unsigned short* __restrict__ Kg_,
    const unsigned short* __restrict__ Vtg_,
    unsigned short* __restrict__ CTX)
{
  // shorts: buf b: K@b*8192[4096] V@b*8192+4096[4096], b=0..2 | P@24576 8x[32*64]
  __shared__ unsigned short smem[40960];   // 81920 B
  const int tid  = threadIdx.x, wave = tid >> 6, lane = tid & 63;
  const int quad = lane >> 4, l15 = lane & 15;
  unsigned short* Pw = smem + 24576 + wave * 2048;
  const int swp = l15 & 7;                 // P chunk swizzle key

  const int bh = (int)blockIdx.x;
  const int yy = (int)blockIdx.y;
  const int qt = (yy < 4) ? yy : (11 - yy);      // pairs (y,y+4) sum to 7
  const int q0 = qt * 256;
  const size_t base = (size_t)bh * (S_LEN * HDIM);
  const unsigned short* Qg  = Qg_  + base;
  const unsigned short* Kg  = Kg_  + base;
  const unsigned short* Vtg = Vtg_ + base;        // [hd][s]
  const int qw = q0 + wave * 32;

  const int strow = lane >> 3;
  const int stxc  = (lane & 7) ^ strow;
  const unsigned short* kstage = Kg  + (size_t)(wave * 8 + strow) * HDIM  + stxc * 8;
  const unsigned short* vstage = Vtg + (size_t)(wave * 8 + strow) * S_LEN + stxc * 8;
  unsigned short* kd0 = smem + wave * 512;
  unsigned short* vd0 = smem + 4096 + wave * 512;

  const int ntiles = 4 * (qt + 1);               // >= 4 always

  // prologue: stage tiles 0,1 -> bufs 0,1
  async_cp16(kstage, kd0);
  async_cp16(vstage, vd0);
  async_cp16(kstage + (size_t)64 * HDIM, kd0 + 8192);
  async_cp16(vstage + 64,                vd0 + 8192);

  // Q fragments direct from global (one-time; B-operand B[n=q][k=dim])
  bf16x8 qf[2][2];
#pragma unroll
  for (int qtile = 0; qtile < 2; qtile++)
#pragma unroll
    for (int ks = 0; ks < 2; ks++)
      qf[qtile][ks] = *(const bf16x8*)&Qg[(size_t)(qw + qtile * 16 + l15) * HDIM + ks * 32 + quad * 8];

  const int sw0 = ((quad)     ^ (l15 & 7)) * 8;  // K/V frag swizzled col offs
  const int sw1 = ((4 + quad) ^ (l15 & 7)) * 8;

  const floatx4 fzero = {0.f, 0.f, 0.f, 0.f};
  floatx4 O[2][4];
  float l_part[2] = {0.f, 0.f};
#pragma unroll
  for (int qtile = 0; qtile < 2; qtile++)
#pragma unroll
    for (int mt = 0; mt < 4; mt++) O[qtile][mt] = fzero;

  auto tile = [&](int j) {
    const int k0 = j * 64;
    if (k0 > qw + 31) return;                    // above diagonal for this wave
    const unsigned short* Ksb = smem + (j % 3) * 8192;
    const unsigned short* Vsb = Ksb + 4096;
    const int krel = qw + 31 - k0;

    bf16x8 kf[4][2];
#pragma unroll
    for (int kt = 0; kt < 4; kt++) {
      if (kt * 16 <= krel) {
        const unsigned short* kr = &Ksb[(kt * 16 + l15) * 64];
        kf[kt][0] = *(const bf16x8*)(kr + sw0);
        kf[kt][1] = *(const bf16x8*)(kr + sw1);
      }
    }

#pragma unroll
    for (int qtile = 0; qtile < 2; qtile++) {
      const int kmax = qw + qtile * 16 + 15;
      if (k0 > kmax) continue;
      floatx4 sa[4];
#pragma unroll
      for (int kt = 0; kt < 4; kt++) sa[kt] = fzero;
#pragma unroll
      for (int kt = 0; kt < 4; kt++) {
        if (k0 + kt * 16 <= kmax) {
          sa[kt] = __builtin_amdgcn_mfma_f32_16x16x32_bf16(kf[kt][0], qf[qtile][0], sa[kt], 0, 0, 0);
          sa[kt] = __builtin_amdgcn_mfma_f32_16x16x32_bf16(kf[kt][1], qf[qtile][1], sa[kt], 0, 0, 0);
        }
      }
      const int qrow = qw + qtile * 16 + l15;
#pragma unroll
      for (int kt = 0; kt < 4; kt++) {
        const int kbase = k0 + kt * 16;
        // P[q][key] stride 64, chunk (kt*2 + quad/2) XOR-swizzled by q&7
        unsigned short* pdst = &Pw[(qtile * 16 + l15) * 64 +
                                   ((kt * 2 + (quad >> 1)) ^ swp) * 8 + (quad & 1) * 4];
        if (kbase <= kmax) {
          if (kbase + 15 > qw + qtile * 16) {
#pragma unroll
            for (int r = 0; r < 4; r++)
              if (kbase + quad * 4 + r > qrow) sa[kt][r] = -INFINITY;
          }
          const float p0 = EXP2F(sa[kt][0]), p1 = EXP2F(sa[kt][1]);
          const float p2 = EXP2F(sa[kt][2]), p3 = EXP2F(sa[kt][3]);
          l_part[qtile] += (p0 + p1) + (p2 + p3);
          uint2 pk; pk.x = pack2bf(p0, p1); pk.y = pack2bf(p2, p3);
          *(uint2*)pdst = pk;
        } else if (k0 + (kt >> 1) * 32 <= kmax) {
          uint2 z; z.x = 0u; z.y = 0u;
          *(uint2*)pdst = z;
        }
      }
    }
    asm volatile("s_waitcnt lgkmcnt(0)" ::: "memory");  // P writes (wave-local)

    // O^T += V^T P^T : A = Vt frag (swizzled LDS), B = P frag (b128, swizzled)
#pragma unroll
    for (int ks = 0; ks < 2; ks++) {
      if (ks * 32 > krel) break;
      bf16x8 vf[4];
#pragma unroll
      for (int mt = 0; mt < 4; mt++)
        vf[mt] = *(const bf16x8*)(&Vsb[(mt * 16 + l15) * 64] + (ks ? sw1 : sw0));
#pragma unroll
      for (int qtile = 0; qtile < 2; qtile++) {
        if (k0 + ks * 32 > qw + qtile * 16 + 15) continue;
        const bf16x8 pv = *(const bf16x8*)&Pw[(qtile * 16 + l15) * 64 +
                                              ((ks * 4 + quad) ^ swp) * 8];
#pragma unroll
        for (int mt = 0; mt < 4; mt++)
          O[qtile][mt] = __builtin_amdgcn_mfma_f32_16x16x32_bf16(vf[mt], pv, O[qtile][mt], 0, 0, 0);
      }
    }
  };

  for (int j = 0; j < ntiles - 1; j++) {
    // wait oldest tile's 2 loads only (newer stay in flight), then barrier
    asm volatile("s_waitcnt vmcnt(2) lgkmcnt(0)\n\ts_barrier" ::: "memory");
    if (j + 2 < ntiles) {
      const int nb = (j + 2) % 3;
      async_cp16(kstage + (size_t)(j + 2) * 64 * HDIM, kd0 + nb * 8192);
      async_cp16(vstage + (size_t)(j + 2) * 64,        vd0 + nb * 8192);
    }
    tile(j);
  }
  asm volatile("s_waitcnt vmcnt(0) lgkmcnt(0)\n\ts_barrier" ::: "memory");
  tile(ntiles - 1);

  // l: reduce partial sums across the 4 quads
#pragma unroll
  for (int d = 16; d < 64; d <<= 1) {
    l_part[0] += __shfl_xor(l_part[0], d, 64);
    l_part[1] += __shfl_xor(l_part[1], d, 64);
  }

  // epilogue: O^T (hd=row, q=col) -> Pw [q][hd] (same XOR-chunk swizzle)
#pragma unroll
  for (int qtile = 0; qtile < 2; qtile++) {
    const float inv = 1.0f / l_part[qtile];
#pragma unroll
    for (int mt = 0; mt < 4; mt++)
#pragma unroll
      for (int a = 0; a < 2; a++) {
        const unsigned int pk =
            (unsigned int)f2bf(O[qtile][mt][2 * a] * inv) |
            ((unsigned int)f2bf(O[qtile][mt][2 * a + 1] * inv) << 16);
        *(unsigned int*)&Pw[(qtile * 16 + l15) * 64 +
                            ((mt * 2 + (quad >> 1)) ^ swp) * 8 + (quad & 1) * 4 + 2 * a] = pk;
      }
  }
  asm volatile("s_waitcnt lgkmcnt(0)" ::: "memory");
  const int b = bh >> 4, h = bh & 15;
#pragma unroll
  for (int it = 0; it < 4; it++) {
    const int g = it * 64 + lane;
    const int row = g >> 3, lc = g & 7;          // logical chunk lc
    const ushort8v ov = *(const ushort8v*)&Pw[row * 64 + (lc ^ (row & 7)) * 8];
    const int s = qw + row;
    *(ushort8v*)&CTX[((size_t)(b * S_LEN + s)) * KD + h * HDIM + lc * 8] = ov;
  }
}

// ---------------------------------------------------------------------------
// Kernel 4: output projection ctx[8192,1024] x W_o[1024,1024]^T + b_o -> fp32
// Same distance-2 pipelined K-loop as gemm_qkv.
// ---------------------------------------------------------------------------
__global__ __launch_bounds__(256) void gemm_out(
    const unsigned short* __restrict__ A,
    const unsigned short* __restrict__ Bw,
    const float* __restrict__ bias,
    float* __restrict__ out)
{
  __shared__ unsigned short smem[24576];   // 3 bufs x (As|Bs)
  const int tid  = threadIdx.x;
  const int wave = tid >> 6, lane = tid & 63;
  const int quad = lane >> 4, l15 = lane & 15;
  const int wr = wave >> 1, wc = wave & 1;
  const int m0 = blockIdx.x * 128, n0 = blockIdx.y * 128;

  const int srow = lane >> 2;
  const int scol = ((lane & 3) ^ ((srow >> 1) & 3)) * 8;
  const unsigned short* gA = A  + (size_t)(m0 + wave * 32 + srow) * KD + scol;
  const unsigned short* gB = Bw + (size_t)(n0 + wave * 32 + srow) * KD + scol;
  unsigned short* lA0 = smem + wave * 1024;
  unsigned short* lB0 = smem + 4096 + wave * 1024;

  const floatx4 fzero = {0.f, 0.f, 0.f, 0.f};
  floatx4 acc[4][4];
#pragma unroll
  for (int i = 0; i < 4; i++)
#pragma unroll
    for (int j = 0; j < 4; j++) acc[i][j] = fzero;

#pragma unroll
  for (int t = 0; t < 2; t++) {
    async_cp16(gA + t * 32,                   lA0 + t * 8192);
    async_cp16(gA + t * 32 + (size_t)16 * KD, lA0 + t * 8192 + 512);
    async_cp16(gB + t * 32,                   lB0 + t * 8192);
    async_cp16(gB + t * 32 + (size_t)16 * KD, lB0 + t * 8192 + 512);
  }
  const int lsw = (l15 >> 1) & 3;

  auto compute = [&](int it) {
    const unsigned short* As = smem + (it % 3) * 8192;
    const unsigned short* Bs = As + 4096;
    bf16x8 af[4], bfrag[4];
#pragma unroll
    for (int i = 0; i < 4; i++)
      af[i] = *(const bf16x8*)&As[(wr * 64 + i * 16 + l15) * 32 + (quad ^ lsw) * 8];
#pragma unroll
    for (int j = 0; j < 4; j++)
      bfrag[j] = *(const bf16x8*)&Bs[(wc * 64 + j * 16 + l15) * 32 + (quad ^ lsw) * 8];
#pragma unroll
    for (int i = 0; i < 4; i++)
#pragma unroll
      for (int j = 0; j < 4; j++)
        acc[i][j] = __builtin_amdgcn_mfma_f32_16x16x32_bf16(af[i], bfrag[j], acc[i][j], 0, 0, 0);
  };

  for (int it = 0; it < 31; it++) {
    asm volatile("s_waitcnt vmcnt(4) lgkmcnt(0)\n\ts_barrier" ::: "memory");
    if (it + 2 < 32) {
      const int nb = (it + 2) % 3;
      const int ko = (it + 2) * 32;
      async_cp16(gA + ko,                   lA0 + nb * 8192);
      async_cp16(gA + ko + (size_t)16 * KD, lA0 + nb * 8192 + 512);
      async_cp16(gB + ko,                   lB0 + nb * 8192);
      async_cp16(gB + ko + (size_t)16 * KD, lB0 + nb * 8192 + 512);
    }
    compute(it);
  }
  asm volatile("s_waitcnt vmcnt(0) lgkmcnt(0)\n\ts_barrier" ::: "memory");
  compute(31);

#pragma unroll
  for (int j = 0; j < 4; j++) {
    const int n = n0 + wc * 64 + j * 16 + l15;
    const float bb = bias[n];
#pragma unroll
    for (int i = 0; i < 4; i++) {
#pragma unroll
      for (int r = 0; r < 4; r++) {
        const int m = m0 + wr * 64 + i * 16 + quad * 4 + r;
        out[(size_t)m * KD + n] = acc[i][j][r] + bb;
      }
    }
  }
}

// ---------------------------------------------------------------------------
extern "C" void kernel_launch(void* const* d_in, const int* in_sizes, int n_in,
                              void* d_out, int out_size, void* d_ws, size_t ws_size,
                              hipStream_t stream) {
  (void)in_sizes; (void)n_in; (void)out_size;
  const float* x  = (const float*)d_in[0];
  const float* wq = (const float*)d_in[1];
  const float* wk = (const float*)d_in[2];
  const float* wv = (const float*)d_in[3];
  const float* wo = (const float*)d_in[4];
  const float* bo = (const float*)d_in[5];
  float* out = (float*)d_out;

  if (ws_size < (size_t)92274688) return;
  char* ws = (char*)d_ws;
  unsigned short* xb    = (unsigned short*)(ws);
  unsigned short* wqkvb = (unsigned short*)(ws + (size_t)16777216);
  unsigned short* wob   = (unsigned short*)(ws + (size_t)23068672);
  unsigned short* qws   = (unsigned short*)(ws + (size_t)25165824);
  unsigned short* kws   = (unsigned short*)(ws + (size_t)41943040);
  unsigned short* vtws  = (unsigned short*)(ws + (size_t)58720256);
  unsigned short* ctxws = (unsigned short*)(ws + (size_t)75497472);

  cvt_kernel<<<12288, 256, 0, stream>>>(x, wq, wk, wv, wo, xb, wqkvb, wob);
  gemm_qkv<<<dim3(64, 24), 256, 0, stream>>>(xb, wqkvb, qws, kws, vtws);
  attn_kernel<<<dim3(64, 8), 512, 0, stream>>>(qws, kws, vtws, ctxws);
  gemm_out<<<dim3(64, 8), 256, 0, stream>>>(ctxws, wob, bo, out);
}

// Round 9
// 257.828 us; speedup vs baseline: 1.0028x; 1.0028x over previous
//
#include <hip/hip_runtime.h>
#include <cstdint>
#include <cstddef>

// Problem constants
#define S_LEN  2048
#define NHEAD  16
#define HDIM   64
#define KD     1024   // D_IN == D_OUT
#define BSROWS 8192   // B * S

typedef __attribute__((ext_vector_type(4))) float          floatx4;
typedef __attribute__((ext_vector_type(8))) __bf16         bf16x8;
typedef __attribute__((ext_vector_type(8))) unsigned short ushort8v;
typedef __attribute__((ext_vector_type(4))) unsigned short ushort4v;
typedef __attribute__((ext_vector_type(4))) float          float4v;

// fp32 -> bf16 round-to-nearest-even on the bit pattern (inputs are finite)
__device__ __forceinline__ unsigned short f2bf(float f) {
  unsigned int u = __float_as_uint(f);
  u += 0x7fffu + ((u >> 16) & 1u);
  return (unsigned short)(u >> 16);
}

// fast exp2 (single v_exp_f32)
#if __has_builtin(__builtin_amdgcn_exp2f)
#define EXP2F(x) __builtin_amdgcn_exp2f(x)
#else
#define EXP2F(x) exp2f(x)
#endif

// pack two fp32 into packed bf16 (truncation; bias cancels in O/l)
__device__ __forceinline__ unsigned int pack2bf(float a, float b) {
#if __has_builtin(__builtin_amdgcn_perm)
  return __builtin_amdgcn_perm(__float_as_uint(b), __float_as_uint(a), 0x07060302);
#else
  return (__float_as_uint(a) >> 16) | (__float_as_uint(b) & 0xffff0000u);
#endif
}

// async global->LDS, 16B per lane; LDS dest is wave-uniform base + lane*16
__device__ __forceinline__ void async_cp16(const void* gsrc, void* ldst) {
  __builtin_amdgcn_global_load_lds(
      (__attribute__((address_space(1))) void*)gsrc,
      (__attribute__((address_space(3))) void*)ldst,
      16, 0, 0);
}

// ---------------------------------------------------------------------------
// Kernel 1: fp32 -> bf16 conversion of x, W_q|W_k|W_v (concat), W_o
// ---------------------------------------------------------------------------
#define XN4 2097152   // B*S*D_IN / 4
#define WN4 262144    // 1024*1024 / 4

__global__ __launch_bounds__(256) void cvt_kernel(
    const float* __restrict__ x,  const float* __restrict__ wq,
    const float* __restrict__ wk, const float* __restrict__ wv,
    const float* __restrict__ wo,
    unsigned short* __restrict__ xb, unsigned short* __restrict__ wqkvb,
    unsigned short* __restrict__ wob)
{
  const int i = blockIdx.x * 256 + threadIdx.x;
  const float* src; unsigned short* dst; int off;
  if (i < XN4) { src = x; dst = xb; off = i; }
  else {
    const int j = i - XN4;
    if (j < WN4)          { src = wq; dst = wqkvb;           off = j; }
    else if (j < 2*WN4)   { src = wk; dst = wqkvb + 4*WN4;   off = j - WN4; }
    else if (j < 3*WN4)   { src = wv; dst = wqkvb + 8*WN4;   off = j - 2*WN4; }
    else                  { src = wo; dst = wob;             off = j - 3*WN4; }
  }
  const float4v v = ((const float4v*)src)[off];
  ushort4v o;
  o.x = f2bf(v.x); o.y = f2bf(v.y); o.z = f2bf(v.z); o.w = f2bf(v.w);
  ((ushort4v*)dst)[off] = o;
}

// ---------------------------------------------------------------------------
// Kernel 2: fused QKV projection, NT bf16 GEMM [8192,1024] x [3072,1024]^T
// R7 structure (measured best): double-buffered async staging, ONE fused
// vmcnt(0)+lgkm barrier per BK=32 iteration, XOR-swizzled staging/frag reads.
// Q/K epilogue: C -> LDS (stride 130) -> coalesced 16B stores [b,h,s,hd].
// V  epilogue: C -> LDS TRANSPOSED (stride 136) -> 16B stores into Vt.
// ---------------------------------------------------------------------------
__global__ __launch_bounds__(256) void gemm_qkv(
    const unsigned short* __restrict__ A,
    const unsigned short* __restrict__ Bw,
    unsigned short* __restrict__ Qo,
    unsigned short* __restrict__ Ko,
    unsigned short* __restrict__ Vto)
{
  // K-loop: buf0 As@0 Bs@4096 | buf1 As@8192 Bs@12288 (shorts)
  // epilogue reuse: Q/K 128*130=16640; V 128*136=17408 shorts
  __shared__ unsigned short smem[17408];
  const int tid  = threadIdx.x;
  const int wave = tid >> 6, lane = tid & 63;
  const int quad = lane >> 4, l15 = lane & 15;
  const int wr = wave >> 1, wc = wave & 1;
  const int m0 = blockIdx.x * 128, n0 = blockIdx.y * 128;

  const int srow = lane >> 2;
  const int scol = ((lane & 3) ^ ((srow >> 1) & 3)) * 8;   // XOR-swizzled source
  const unsigned short* gA = A  + (size_t)(m0 + wave * 32 + srow) * KD + scol;
  const unsigned short* gB = Bw + (size_t)(n0 + wave * 32 + srow) * KD + scol;

  const floatx4 fzero = {0.f, 0.f, 0.f, 0.f};
  floatx4 acc[4][4];
#pragma unroll
  for (int i = 0; i < 4; i++)
#pragma unroll
    for (int j = 0; j < 4; j++) acc[i][j] = fzero;

  // prologue: stage K-tile 0 -> buf0
  {
    unsigned short* lA = smem + wave * 1024;
    unsigned short* lB = smem + 4096 + wave * 1024;
    async_cp16(gA,                    lA);
    async_cp16(gA + (size_t)16 * KD,  lA + 512);
    async_cp16(gB,                    lB);
    async_cp16(gB + (size_t)16 * KD,  lB + 512);
  }
  const int lsw = (l15 >> 1) & 3;    // loop-invariant frag-read swizzle

#pragma unroll 2
  for (int it = 0; it < 32; it++) {
    asm volatile("s_waitcnt vmcnt(0) lgkmcnt(0)\n\ts_barrier" ::: "memory");
    if (it + 1 < 32) {               // prefetch K-tile it+1 -> buf^1
      const int nb = (it + 1) & 1;
      const int ko = (it + 1) * 32;
      unsigned short* lA = smem + nb * 8192 + wave * 1024;
      unsigned short* lB = smem + nb * 8192 + 4096 + wave * 1024;
      async_cp16(gA + ko,                   lA);
      async_cp16(gA + ko + (size_t)16 * KD, lA + 512);
      async_cp16(gB + ko,                   lB);
      async_cp16(gB + ko + (size_t)16 * KD, lB + 512);
    }
    const unsigned short* As = smem + (it & 1) * 8192;
    const unsigned short* Bs = As + 4096;

    bf16x8 af[4], bfrag[4];
#pragma unroll
    for (int i = 0; i < 4; i++)
      af[i] = *(const bf16x8*)&As[(wr * 64 + i * 16 + l15) * 32 + (quad ^ lsw) * 8];
#pragma unroll
    for (int j = 0; j < 4; j++)
      bfrag[j] = *(const bf16x8*)&Bs[(wc * 64 + j * 16 + l15) * 32 + (quad ^ lsw) * 8];
#pragma unroll
    for (int i = 0; i < 4; i++)
#pragma unroll
      for (int j = 0; j < 4; j++)
        acc[i][j] = __builtin_amdgcn_mfma_f32_16x16x32_bf16(af[i], bfrag[j], acc[i][j], 0, 0, 0);
  }

  const int which = n0 >> 10;                     // 0:Q 1:K 2:V
  const int h0 = (n0 & 1023) >> 6;                // first head of this n-block
  const int b = m0 >> 11, sl = m0 & 2047;

  if (which < 2) {
    unsigned short* dst = which ? Ko : Qo;
    const float scale = which ? 1.0f : 0.18033688011112042f;  // Q: 0.125*log2(e)
    __syncthreads();                              // staging dead -> reuse as Ct[s][n]
    const int crow = wr * 64 + quad * 4;
    const int ccol = wc * 64 + l15;
#pragma unroll
    for (int i = 0; i < 4; i++)
#pragma unroll
      for (int j = 0; j < 4; j++)
#pragma unroll
        for (int r = 0; r < 4; r++)
          smem[(crow + i * 16 + r) * 130 + ccol + j * 16] = f2bf(acc[i][j][r] * scale);
    __syncthreads();
#pragma unroll
    for (int t = 0; t < 8; t++) {
      const int c   = t * 256 + tid;
      const int hd8 = (c & 7) * 8;
      const int hh  = (c >> 3) & 1;
      const int s   = c >> 4;
      const ushort8v val = *(const ushort8v*)&smem[s * 130 + hh * 64 + hd8];
      *(ushort8v*)&dst[((size_t)((b * NHEAD + h0 + hh) * S_LEN + sl + s)) * HDIM + hd8] = val;
    }
  } else {
    // V: stage TRANSPOSED Ct[n][s] (stride 136), then Vt[b,h,hd,s] stores.
    __syncthreads();
    const int crow = wr * 64 + quad * 4;          // s_local
    const int ccol = wc * 64 + l15;               // n_local
#pragma unroll
    for (int i = 0; i < 4; i++)
#pragma unroll
      for (int j = 0; j < 4; j++) {
        ushort4v t4;
#pragma unroll
        for (int r = 0; r < 4; r++) t4[r] = f2bf(acc[i][j][r]);
        *(ushort4v*)&smem[(ccol + j * 16) * 136 + crow + i * 16] = t4;
      }
    __syncthreads();
#pragma unroll
    for (int t = 0; t < 8; t++) {
      const int c  = t * 256 + tid;
      const int nl = c >> 4, sc = (c & 15) * 8;
      const ushort8v val = *(const ushort8v*)&smem[nl * 136 + sc];
      *(ushort8v*)&Vto[((size_t)((b * NHEAD + h0 + (nl >> 6)) * HDIM + (nl & 63))) * S_LEN + sl + sc] = val;
    }
  }
}

// ---------------------------------------------------------------------------
// Kernel 3: causal flash attention, S^T formulation, ASYNC-PIPELINED.
// R9: 256 thr = 4 waves (was 8) -> LDS 50176 B -> THREE independent barrier
// domains per CU (was 2 of 8 waves): smaller blast radius for each per-tile
// serial chain (barrier -> ds_read -> MFMA -> exp2 -> lgkm -> PV), better
// cross-block latency overlap. Everything else is R7's measured-best config:
// double-buffered K/V via global_load_lds + XOR source swizzle (0 conflicts),
// ONE fused vmcnt(0)+lgkm barrier per 64-key tile, distance-1 prefetch,
// P stride-68 b64 round-trip, no running max (exp2 domain, scale in Q).
// Grid (x=bh 64, y=16 qt): bh-major for XCD L2 residency; qt perm makes
// {y, y+4, y+8, y+12} workloads sum equal (CU gets balanced 4-block stream).
// ---------------------------------------------------------------------------
__global__ __launch_bounds__(256, 3) void attn_kernel(
    const unsigned short* __restrict__ Qg_,
    const unsigned short* __restrict__ Kg_,
    const unsigned short* __restrict__ Vtg_,
    unsigned short* __restrict__ CTX)
{
  // shorts: buf0 K@0[4096] V@4096[4096] | buf1 K@8192 V@12288 | P@16384 4x[32*68]
  __shared__ unsigned short smem[25088];   // 50176 B
  const int tid  = threadIdx.x, wave = tid >> 6, lane = tid & 63;
  const int quad = lane >> 4, l15 = lane & 15;
  unsigned short* Pw = smem + 16384 + wave * 2176;

  const int bh = (int)blockIdx.x;
  const int yy = (int)blockIdx.y;
  // qt perm: {0,1,2,3, 7,6,5,4, 8,9,10,11, 15,14,13,12} — columns sum to 30
  const int qt = (yy < 4) ? yy : (yy < 8) ? (11 - yy) : (yy < 12) ? yy : (27 - yy);
  const int q0 = qt * 128;
  const size_t base = (size_t)bh * (S_LEN * HDIM);
  const unsigned short* Qg  = Qg_  + base;
  const unsigned short* Kg  = Kg_  + base;
  const unsigned short* Vtg = Vtg_ + base;        // [hd][s]
  const int qw = q0 + wave * 32;

  // staging: wave w covers 16 rows (two 8-row cp16 groups); lane row=lane>>3,
  // chunk slot lane&7 holds global col-chunk (slot ^ row)  (XOR at source).
  const int strow = lane >> 3;
  const int stxc  = (lane & 7) ^ strow;
  const unsigned short* kstage = Kg  + (size_t)(wave * 16 + strow) * HDIM  + stxc * 8;
  const unsigned short* vstage = Vtg + (size_t)(wave * 16 + strow) * S_LEN + stxc * 8;
  unsigned short* kd0 = smem + wave * 1024;        // wave-uniform LDS dests
  unsigned short* vd0 = smem + 4096 + wave * 1024;

  // prologue: async stage tile 0 -> buf 0 (K rows w*16..+15, V same)
  async_cp16(kstage,                       kd0);
  async_cp16(kstage + (size_t)8 * HDIM,    kd0 + 512);
  async_cp16(vstage,                       vd0);
  async_cp16(vstage + (size_t)8 * S_LEN,   vd0 + 512);

  // Q fragments direct from global (one-time; B-operand B[n=q][k=dim])
  bf16x8 qf[2][2];
#pragma unroll
  for (int qtile = 0; qtile < 2; qtile++)
#pragma unroll
    for (int ks = 0; ks < 2; ks++)
      qf[qtile][ks] = *(const bf16x8*)&Qg[(size_t)(qw + qtile * 16 + l15) * HDIM + ks * 32 + quad * 8];

  const int sw0 = ((quad)     ^ (l15 & 7)) * 8;
  const int sw1 = ((4 + quad) ^ (l15 & 7)) * 8;

  const floatx4 fzero = {0.f, 0.f, 0.f, 0.f};
  floatx4 O[2][4];
  float l_part[2] = {0.f, 0.f};
#pragma unroll
  for (int qtile = 0; qtile < 2; qtile++)
#pragma unroll
    for (int mt = 0; mt < 4; mt++) O[qtile][mt] = fzero;

  const int ntiles = 2 * (qt + 1);

  for (int j = 0; j < ntiles; j++) {
    asm volatile("s_waitcnt vmcnt(0) lgkmcnt(0)\n\ts_barrier" ::: "memory");
    if (j + 1 < ntiles) {
      const int nb = (j + 1) & 1;
      const unsigned short* kp = kstage + (size_t)(j + 1) * 64 * HDIM;
      const unsigned short* vp = vstage + (size_t)(j + 1) * 64;
      async_cp16(kp,                     kd0 + nb * 8192);
      async_cp16(kp + (size_t)8 * HDIM,  kd0 + nb * 8192 + 512);
      async_cp16(vp,                     vd0 + nb * 8192);
      async_cp16(vp + (size_t)8 * S_LEN, vd0 + nb * 8192 + 512);
    }
    const int k0 = j * 64;
    if (k0 > qw + 31) continue;
    const unsigned short* Ksb = smem + (j & 1) * 8192;
    const unsigned short* Vsb = Ksb + 4096;
    const int krel = qw + 31 - k0;

    bf16x8 kf[4][2];
#pragma unroll
    for (int kt = 0; kt < 4; kt++) {
      if (kt * 16 <= krel) {
        const unsigned short* kr = &Ksb[(kt * 16 + l15) * 64];
        kf[kt][0] = *(const bf16x8*)(kr + sw0);
        kf[kt][1] = *(const bf16x8*)(kr + sw1);
      }
    }

#pragma unroll
    for (int qtile = 0; qtile < 2; qtile++) {
      const int kmax = qw + qtile * 16 + 15;
      if (k0 > kmax) continue;
      floatx4 sa[4];
#pragma unroll
      for (int kt = 0; kt < 4; kt++) sa[kt] = fzero;
#pragma unroll
      for (int kt = 0; kt < 4; kt++) {
        if (k0 + kt * 16 <= kmax) {
          sa[kt] = __builtin_amdgcn_mfma_f32_16x16x32_bf16(kf[kt][0], qf[qtile][0], sa[kt], 0, 0, 0);
          sa[kt] = __builtin_amdgcn_mfma_f32_16x16x32_bf16(kf[kt][1], qf[qtile][1], sa[kt], 0, 0, 0);
        }
      }
      const int qrow = qw + qtile * 16 + l15;
#pragma unroll
      for (int kt = 0; kt < 4; kt++) {
        const int kbase = k0 + kt * 16;
        unsigned short* pdst = &Pw[(qtile * 16 + l15) * 68 + kt * 16 + quad * 4];
        if (kbase <= kmax) {
          if (kbase + 15 > qw + qtile * 16) {
#pragma unroll
            for (int r = 0; r < 4; r++)
              if (kbase + quad * 4 + r > qrow) sa[kt][r] = -INFINITY;
          }
          const float p0 = EXP2F(sa[kt][0]), p1 = EXP2F(sa[kt][1]);
          const float p2 = EXP2F(sa[kt][2]), p3 = EXP2F(sa[kt][3]);
          l_part[qtile] += (p0 + p1) + (p2 + p3);
          uint2 pk; pk.x = pack2bf(p0, p1); pk.y = pack2bf(p2, p3);
          *(uint2*)pdst = pk;
        } else if (k0 + (kt >> 1) * 32 <= kmax) {
          uint2 z; z.x = 0u; z.y = 0u;
          *(uint2*)pdst = z;
        }
      }
    }
    asm volatile("s_waitcnt lgkmcnt(0)" ::: "memory");

#pragma unroll
    for (int ks = 0; ks < 2; ks++) {
      if (ks * 32 > krel) break;
      bf16x8 vf[4];
#pragma unroll
      for (int mt = 0; mt < 4; mt++)
        vf[mt] = *(const bf16x8*)(&Vsb[(mt * 16 + l15) * 64] + (ks ? sw1 : sw0));
#pragma unroll
      for (int qtile = 0; qtile < 2; qtile++) {
        if (k0 + ks * 32 > qw + qtile * 16 + 15) continue;
        const unsigned short* ps = &Pw[(qtile * 16 + l15) * 68 + ks * 32 + quad * 8];
        union { ushort4v h[2]; bf16x8 v; } pu;
        pu.h[0] = *(const ushort4v*)ps;
        pu.h[1] = *(const ushort4v*)(ps + 4);
#pragma unroll
        for (int mt = 0; mt < 4; mt++)
          O[qtile][mt] = __builtin_amdgcn_mfma_f32_16x16x32_bf16(vf[mt], pu.v, O[qtile][mt], 0, 0, 0);
      }
    }
  }

#pragma unroll
  for (int d = 16; d < 64; d <<= 1) {
    l_part[0] += __shfl_xor(l_part[0], d, 64);
    l_part[1] += __shfl_xor(l_part[1], d, 64);
  }

  // epilogue: O^T (hd=row, q=col) -> Pw [q][hd] stride 68 -> coalesced CTX
#pragma unroll
  for (int qtile = 0; qtile < 2; qtile++) {
    const float inv = 1.0f / l_part[qtile];
#pragma unroll
    for (int mt = 0; mt < 4; mt++)
#pragma unroll
      for (int a = 0; a < 2; a++) {
        const unsigned int pk =
            (unsigned int)f2bf(O[qtile][mt][2 * a] * inv) |
            ((unsigned int)f2bf(O[qtile][mt][2 * a + 1] * inv) << 16);
        *(unsigned int*)&Pw[(qtile * 16 + l15) * 68 + mt * 16 + quad * 4 + 2 * a] = pk;
      }
  }
  asm volatile("s_waitcnt lgkmcnt(0)" ::: "memory");
  const int b = bh >> 4, h = bh & 15;
#pragma unroll
  for (int it = 0; it < 4; it++) {
    const int g = it * 64 + lane;
    const int row = g >> 3, c8 = (g & 7) * 8;
    union { ushort4v h[2]; ushort8v v; } ou;
    ou.h[0] = *(const ushort4v*)&Pw[row * 68 + c8];
    ou.h[1] = *(const ushort4v*)&Pw[row * 68 + c8 + 4];
    const int s = qw + row;
    *(ushort8v*)&CTX[((size_t)(b * S_LEN + s)) * KD + h * HDIM + c8] = ou.v;
  }
}

// ---------------------------------------------------------------------------
// Kernel 4: output projection ctx[8192,1024] x W_o[1024,1024]^T + b_o -> fp32
// R7 async-pipelined K-loop (double buffer, distance-1).
// ---------------------------------------------------------------------------
__global__ __launch_bounds__(256) void gemm_out(
    const unsigned short* __restrict__ A,
    const unsigned short* __restrict__ Bw,
    const float* __restrict__ bias,
    float* __restrict__ out)
{
  __shared__ unsigned short smem[16384];   // buf0 As|Bs, buf1 As|Bs
  const int tid  = threadIdx.x;
  const int wave = tid >> 6, lane = tid & 63;
  const int quad = lane >> 4, l15 = lane & 15;
  const int wr = wave >> 1, wc = wave & 1;
  const int m0 = blockIdx.x * 128, n0 = blockIdx.y * 128;

  const int srow = lane >> 2;
  const int scol = ((lane & 3) ^ ((srow >> 1) & 3)) * 8;
  const unsigned short* gA = A  + (size_t)(m0 + wave * 32 + srow) * KD + scol;
  const unsigned short* gB = Bw + (size_t)(n0 + wave * 32 + srow) * KD + scol;

  const floatx4 fzero = {0.f, 0.f, 0.f, 0.f};
  floatx4 acc[4][4];
#pragma unroll
  for (int i = 0; i < 4; i++)
#pragma unroll
    for (int j = 0; j < 4; j++) acc[i][j] = fzero;

  {
    unsigned short* lA = smem + wave * 1024;
    unsigned short* lB = smem + 4096 + wave * 1024;
    async_cp16(gA,                    lA);
    async_cp16(gA + (size_t)16 * KD,  lA + 512);
    async_cp16(gB,                    lB);
    async_cp16(gB + (size_t)16 * KD,  lB + 512);
  }
  const int lsw = (l15 >> 1) & 3;

#pragma unroll 2
  for (int it = 0; it < 32; it++) {
    asm volatile("s_waitcnt vmcnt(0) lgkmcnt(0)\n\ts_barrier" ::: "memory");
    if (it + 1 < 32) {
      const int nb = (it + 1) & 1;
      const int ko = (it + 1) * 32;
      unsigned short* lA = smem + nb * 8192 + wave * 1024;
      unsigned short* lB = smem + nb * 8192 + 4096 + wave * 1024;
      async_cp16(gA + ko,                   lA);
      async_cp16(gA + ko + (size_t)16 * KD, lA + 512);
      async_cp16(gB + ko,                   lB);
      async_cp16(gB + ko + (size_t)16 * KD, lB + 512);
    }
    const unsigned short* As = smem + (it & 1) * 8192;
    const unsigned short* Bs = As + 4096;

    bf16x8 af[4], bfrag[4];
#pragma unroll
    for (int i = 0; i < 4; i++)
      af[i] = *(const bf16x8*)&As[(wr * 64 + i * 16 + l15) * 32 + (quad ^ lsw) * 8];
#pragma unroll
    for (int j = 0; j < 4; j++)
      bfrag[j] = *(const bf16x8*)&Bs[(wc * 64 + j * 16 + l15) * 32 + (quad ^ lsw) * 8];
#pragma unroll
    for (int i = 0; i < 4; i++)
#pragma unroll
      for (int j = 0; j < 4; j++)
        acc[i][j] = __builtin_amdgcn_mfma_f32_16x16x32_bf16(af[i], bfrag[j], acc[i][j], 0, 0, 0);
  }

#pragma unroll
  for (int j = 0; j < 4; j++) {
    const int n = n0 + wc * 64 + j * 16 + l15;
    const float bb = bias[n];
#pragma unroll
    for (int i = 0; i < 4; i++) {
#pragma unroll
      for (int r = 0; r < 4; r++) {
        const int m = m0 + wr * 64 + i * 16 + quad * 4 + r;
        out[(size_t)m * KD + n] = acc[i][j][r] + bb;
      }
    }
  }
}

// ---------------------------------------------------------------------------
extern "C" void kernel_launch(void* const* d_in, const int* in_sizes, int n_in,
                              void* d_out, int out_size, void* d_ws, size_t ws_size,
                              hipStream_t stream) {
  (void)in_sizes; (void)n_in; (void)out_size;
  const float* x  = (const float*)d_in[0];
  const float* wq = (const float*)d_in[1];
  const float* wk = (const float*)d_in[2];
  const float* wv = (const float*)d_in[3];
  const float* wo = (const float*)d_in[4];
  const float* bo = (const float*)d_in[5];
  float* out = (float*)d_out;

  if (ws_size < (size_t)92274688) return;
  char* ws = (char*)d_ws;
  unsigned short* xb    = (unsigned short*)(ws);
  unsigned short* wqkvb = (unsigned short*)(ws + (size_t)16777216);
  unsigned short* wob   = (unsigned short*)(ws + (size_t)23068672);
  unsigned short* qws   = (unsigned short*)(ws + (size_t)25165824);
  unsigned short* kws   = (unsigned short*)(ws + (size_t)41943040);
  unsigned short* vtws  = (unsigned short*)(ws + (size_t)58720256);
  unsigned short* ctxws = (unsigned short*)(ws + (size_t)75497472);

  cvt_kernel<<<12288, 256, 0, stream>>>(x, wq, wk, wv, wo, xb, wqkvb, wob);
  gemm_qkv<<<dim3(64, 24), 256, 0, stream>>>(xb, wqkvb, qws, kws, vtws);
  attn_kernel<<<dim3(64, 16), 256, 0, stream>>>(qws, kws, vtws, ctxws);
  gemm_out<<<dim3(64, 8), 256, 0, stream>>>(ctxws, wob, bo, out);
}

// Round 10
// 242.300 us; speedup vs baseline: 1.0670x; 1.0641x over previous
//
#include <hip/hip_runtime.h>
#include <cstdint>
#include <cstddef>

// Problem constants
#define S_LEN  2048
#define NHEAD  16
#define HDIM   64
#define KD     1024   // D_IN == D_OUT
#define BSROWS 8192   // B * S

typedef __attribute__((ext_vector_type(4))) float          floatx4;
typedef __attribute__((ext_vector_type(8))) __bf16         bf16x8;
typedef __attribute__((ext_vector_type(8))) unsigned short ushort8v;
typedef __attribute__((ext_vector_type(4))) unsigned short ushort4v;
typedef __attribute__((ext_vector_type(4))) float          float4v;

// fp32 -> bf16 round-to-nearest-even on the bit pattern (inputs are finite)
__device__ __forceinline__ unsigned short f2bf(float f) {
  unsigned int u = __float_as_uint(f);
  u += 0x7fffu + ((u >> 16) & 1u);
  return (unsigned short)(u >> 16);
}

// fast exp2 (single v_exp_f32)
#if __has_builtin(__builtin_amdgcn_exp2f)
#define EXP2F(x) __builtin_amdgcn_exp2f(x)
#else
#define EXP2F(x) exp2f(x)
#endif

// pack two fp32 into packed bf16 (truncation; bias cancels in O/l)
__device__ __forceinline__ unsigned int pack2bf(float a, float b) {
#if __has_builtin(__builtin_amdgcn_perm)
  return __builtin_amdgcn_perm(__float_as_uint(b), __float_as_uint(a), 0x07060302);
#else
  return (__float_as_uint(a) >> 16) | (__float_as_uint(b) & 0xffff0000u);
#endif
}

// async global->LDS, 16B per lane; LDS dest is wave-uniform base + lane*16
__device__ __forceinline__ void async_cp16(const void* gsrc, void* ldst) {
  __builtin_amdgcn_global_load_lds(
      (__attribute__((address_space(1))) void*)gsrc,
      (__attribute__((address_space(3))) void*)ldst,
      16, 0, 0);
}

// ---------------------------------------------------------------------------
// Kernel 1: fp32 -> bf16 conversion of x, W_q|W_k|W_v (concat), W_o
// ---------------------------------------------------------------------------
#define XN4 2097152   // B*S*D_IN / 4
#define WN4 262144    // 1024*1024 / 4

__global__ __launch_bounds__(256) void cvt_kernel(
    const float* __restrict__ x,  const float* __restrict__ wq,
    const float* __restrict__ wk, const float* __restrict__ wv,
    const float* __restrict__ wo,
    unsigned short* __restrict__ xb, unsigned short* __restrict__ wqkvb,
    unsigned short* __restrict__ wob)
{
  const int i = blockIdx.x * 256 + threadIdx.x;
  const float* src; unsigned short* dst; int off;
  if (i < XN4) { src = x; dst = xb; off = i; }
  else {
    const int j = i - XN4;
    if (j < WN4)          { src = wq; dst = wqkvb;           off = j; }
    else if (j < 2*WN4)   { src = wk; dst = wqkvb + 4*WN4;   off = j - WN4; }
    else if (j < 3*WN4)   { src = wv; dst = wqkvb + 8*WN4;   off = j - 2*WN4; }
    else                  { src = wo; dst = wob;             off = j - 3*WN4; }
  }
  const float4v v = ((const float4v*)src)[off];
  ushort4v o;
  o.x = f2bf(v.x); o.y = f2bf(v.y); o.z = f2bf(v.z); o.w = f2bf(v.w);
  ((ushort4v*)dst)[off] = o;
}

// ---------------------------------------------------------------------------
// Kernel 2: fused QKV projection, NT bf16 GEMM [8192,1024] x [3072,1024]^T
// R7 structure (measured best): double-buffered async staging, ONE fused
// vmcnt(0)+lgkm barrier per BK=32 iteration, XOR-swizzled staging/frag reads.
// Q/K epilogue: C -> LDS (stride 130) -> coalesced 16B stores [b,h,s,hd].
// V  epilogue: C -> LDS TRANSPOSED (stride 136) -> 16B stores into Vt.
// ---------------------------------------------------------------------------
__global__ __launch_bounds__(256) void gemm_qkv(
    const unsigned short* __restrict__ A,
    const unsigned short* __restrict__ Bw,
    unsigned short* __restrict__ Qo,
    unsigned short* __restrict__ Ko,
    unsigned short* __restrict__ Vto)
{
  __shared__ unsigned short smem[17408];
  const int tid  = threadIdx.x;
  const int wave = tid >> 6, lane = tid & 63;
  const int quad = lane >> 4, l15 = lane & 15;
  const int wr = wave >> 1, wc = wave & 1;
  const int m0 = blockIdx.x * 128, n0 = blockIdx.y * 128;

  const int srow = lane >> 2;
  const int scol = ((lane & 3) ^ ((srow >> 1) & 3)) * 8;   // XOR-swizzled source
  const unsigned short* gA = A  + (size_t)(m0 + wave * 32 + srow) * KD + scol;
  const unsigned short* gB = Bw + (size_t)(n0 + wave * 32 + srow) * KD + scol;

  const floatx4 fzero = {0.f, 0.f, 0.f, 0.f};
  floatx4 acc[4][4];
#pragma unroll
  for (int i = 0; i < 4; i++)
#pragma unroll
    for (int j = 0; j < 4; j++) acc[i][j] = fzero;

  {
    unsigned short* lA = smem + wave * 1024;
    unsigned short* lB = smem + 4096 + wave * 1024;
    async_cp16(gA,                    lA);
    async_cp16(gA + (size_t)16 * KD,  lA + 512);
    async_cp16(gB,                    lB);
    async_cp16(gB + (size_t)16 * KD,  lB + 512);
  }
  const int lsw = (l15 >> 1) & 3;

#pragma unroll 2
  for (int it = 0; it < 32; it++) {
    asm volatile("s_waitcnt vmcnt(0) lgkmcnt(0)\n\ts_barrier" ::: "memory");
    if (it + 1 < 32) {
      const int nb = (it + 1) & 1;
      const int ko = (it + 1) * 32;
      unsigned short* lA = smem + nb * 8192 + wave * 1024;
      unsigned short* lB = smem + nb * 8192 + 4096 + wave * 1024;
      async_cp16(gA + ko,                   lA);
      async_cp16(gA + ko + (size_t)16 * KD, lA + 512);
      async_cp16(gB + ko,                   lB);
      async_cp16(gB + ko + (size_t)16 * KD, lB + 512);
    }
    const unsigned short* As = smem + (it & 1) * 8192;
    const unsigned short* Bs = As + 4096;

    bf16x8 af[4], bfrag[4];
#pragma unroll
    for (int i = 0; i < 4; i++)
      af[i] = *(const bf16x8*)&As[(wr * 64 + i * 16 + l15) * 32 + (quad ^ lsw) * 8];
#pragma unroll
    for (int j = 0; j < 4; j++)
      bfrag[j] = *(const bf16x8*)&Bs[(wc * 64 + j * 16 + l15) * 32 + (quad ^ lsw) * 8];
#pragma unroll
    for (int i = 0; i < 4; i++)
#pragma unroll
      for (int j = 0; j < 4; j++)
        acc[i][j] = __builtin_amdgcn_mfma_f32_16x16x32_bf16(af[i], bfrag[j], acc[i][j], 0, 0, 0);
  }

  const int which = n0 >> 10;                     // 0:Q 1:K 2:V
  const int h0 = (n0 & 1023) >> 6;                // first head of this n-block
  const int b = m0 >> 11, sl = m0 & 2047;

  if (which < 2) {
    unsigned short* dst = which ? Ko : Qo;
    const float scale = which ? 1.0f : 0.18033688011112042f;  // Q: 0.125*log2(e)
    __syncthreads();                              // staging dead -> reuse as Ct[s][n]
    const int crow = wr * 64 + quad * 4;
    const int ccol = wc * 64 + l15;
#pragma unroll
    for (int i = 0; i < 4; i++)
#pragma unroll
      for (int j = 0; j < 4; j++)
#pragma unroll
        for (int r = 0; r < 4; r++)
          smem[(crow + i * 16 + r) * 130 + ccol + j * 16] = f2bf(acc[i][j][r] * scale);
    __syncthreads();
#pragma unroll
    for (int t = 0; t < 8; t++) {
      const int c   = t * 256 + tid;
      const int hd8 = (c & 7) * 8;
      const int hh  = (c >> 3) & 1;
      const int s   = c >> 4;
      const ushort8v val = *(const ushort8v*)&smem[s * 130 + hh * 64 + hd8];
      *(ushort8v*)&dst[((size_t)((b * NHEAD + h0 + hh) * S_LEN + sl + s)) * HDIM + hd8] = val;
    }
  } else {
    // V: stage TRANSPOSED Ct[n][s] (stride 136), then Vt[b,h,hd,s] stores.
    __syncthreads();
    const int crow = wr * 64 + quad * 4;          // s_local
    const int ccol = wc * 64 + l15;               // n_local
#pragma unroll
    for (int i = 0; i < 4; i++)
#pragma unroll
      for (int j = 0; j < 4; j++) {
        ushort4v t4;
#pragma unroll
        for (int r = 0; r < 4; r++) t4[r] = f2bf(acc[i][j][r]);
        *(ushort4v*)&smem[(ccol + j * 16) * 136 + crow + i * 16] = t4;
      }
    __syncthreads();
#pragma unroll
    for (int t = 0; t < 8; t++) {
      const int c  = t * 256 + tid;
      const int nl = c >> 4, sc = (c & 15) * 8;
      const ushort8v val = *(const ushort8v*)&smem[nl * 136 + sc];
      *(ushort8v*)&Vto[((size_t)((b * NHEAD + h0 + (nl >> 6)) * HDIM + (nl & 63))) * S_LEN + sl + sc] = val;
    }
  }
}

// ---------------------------------------------------------------------------
// Kernel 3: causal flash attention, S^T formulation, ASYNC-PIPELINED.
// R10: 512 thr = 8 waves over a 128-row Q tile (wave owns 16 q) — R7's
// per-block wave count but HALF the q per wave: P shrinks to 8x[16x68] so
// LDS = 50176 B -> THREE blocks/CU = 24 waves (R7 had 16). Grid 1024 blocks
// = 4/CU stream: small blocks finishing early get their slot REFILLED
// (fixes R7's 1.8x tail where the 32-tile qt=7 block ran alone).
// Everything else R7-identical: async double-buffered K/V via
// global_load_lds + XOR source swizzle (0 conflicts), ONE fused
// vmcnt(0)+lgkm barrier per 64-key tile, distance-1 prefetch, P stride-68
// b64 round-trip, no running max (exp2 domain, scale folded into Q).
// Grid (x=bh 64, y=16 qt): bh-major for XCD L2 residency; qt perm makes
// {y,y+4,y+8,y+12} sums equal -> every CU's 4-block stream is balanced.
// ---------------------------------------------------------------------------
__global__ __launch_bounds__(512, 6) void attn_kernel(
    const unsigned short* __restrict__ Qg_,
    const unsigned short* __restrict__ Kg_,
    const unsigned short* __restrict__ Vtg_,
    unsigned short* __restrict__ CTX)
{
  // shorts: buf0 K@0[4096] V@4096[4096] | buf1 K@8192 V@12288 | P@16384 8x[16*68]
  __shared__ unsigned short smem[25088];   // 50176 B
  const int tid  = threadIdx.x, wave = tid >> 6, lane = tid & 63;
  const int quad = lane >> 4, l15 = lane & 15;
  unsigned short* Pw = smem + 16384 + wave * 1088;   // [16][68] per wave

  const int bh = (int)blockIdx.x;
  const int yy = (int)blockIdx.y;
  // qt perm: {0,1,2,3, 7,6,5,4, 8,9,10,11, 15,14,13,12} — columns sum to 30
  const int qt = (yy < 4) ? yy : (yy < 8) ? (11 - yy) : (yy < 12) ? yy : (27 - yy);
  const int q0 = qt * 128;
  const size_t base = (size_t)bh * (S_LEN * HDIM);
  const unsigned short* Qg  = Qg_  + base;
  const unsigned short* Kg  = Kg_  + base;
  const unsigned short* Vtg = Vtg_ + base;        // [hd][s]
  const int qw = q0 + wave * 16;                  // wave's 16 q-rows

  // staging (R7 layout): wave w covers tile-rows w*8..w*8+7; lane row=lane>>3,
  // chunk slot lane&7 holds global col-chunk (slot ^ row)  (XOR at source).
  const int strow = lane >> 3;
  const int stxc  = (lane & 7) ^ strow;
  const unsigned short* kstage = Kg  + (size_t)(wave * 8 + strow) * HDIM  + stxc * 8;
  const unsigned short* vstage = Vtg + (size_t)(wave * 8 + strow) * S_LEN + stxc * 8;
  unsigned short* kd0 = smem + wave * 512;
  unsigned short* vd0 = smem + 4096 + wave * 512;

  // prologue: async stage tile 0 -> buf 0
  async_cp16(kstage, kd0);
  async_cp16(vstage, vd0);

  // Q fragments direct from global (one-time; B-operand B[n=q][k=dim])
  bf16x8 qf[2];
#pragma unroll
  for (int ks = 0; ks < 2; ks++)
    qf[ks] = *(const bf16x8*)&Qg[(size_t)(qw + l15) * HDIM + ks * 32 + quad * 8];

  const int sw0 = ((quad)     ^ (l15 & 7)) * 8;   // K/V frag swizzled col offs
  const int sw1 = ((4 + quad) ^ (l15 & 7)) * 8;

  const floatx4 fzero = {0.f, 0.f, 0.f, 0.f};
  floatx4 O[4];
  float l_part = 0.f;
#pragma unroll
  for (int mt = 0; mt < 4; mt++) O[mt] = fzero;

  const int ntiles = 2 * qt + 2;   // covers keys 0..q0+127 >= qw+15

  for (int j = 0; j < ntiles; j++) {
    asm volatile("s_waitcnt vmcnt(0) lgkmcnt(0)\n\ts_barrier" ::: "memory");
    if (j + 1 < ntiles) {
      const int nb = (j + 1) & 1;
      async_cp16(kstage + (size_t)(j + 1) * 64 * HDIM, kd0 + nb * 8192);
      async_cp16(vstage + (size_t)(j + 1) * 64,        vd0 + nb * 8192);
    }
    const int k0 = j * 64;
    if (k0 > qw + 15) continue;                 // above diagonal for this wave
    const unsigned short* Ksb = smem + (j & 1) * 8192;
    const unsigned short* Vsb = Ksb + 4096;
    const int krel = qw + 15 - k0;              // max key offset needed

    // S^T = K Q^T  (A = K frag just-in-time, B = Q reg frag)
    floatx4 sa[4];
#pragma unroll
    for (int kt = 0; kt < 4; kt++) sa[kt] = fzero;
#pragma unroll
    for (int kt = 0; kt < 4; kt++) {
      if (kt * 16 <= krel) {
        const unsigned short* kr = &Ksb[(kt * 16 + l15) * 64];
        sa[kt] = __builtin_amdgcn_mfma_f32_16x16x32_bf16(*(const bf16x8*)(kr + sw0), qf[0], sa[kt], 0, 0, 0);
        sa[kt] = __builtin_amdgcn_mfma_f32_16x16x32_bf16(*(const bf16x8*)(kr + sw1), qf[1], sa[kt], 0, 0, 0);
      }
    }

    const int qrow = qw + l15;                  // this lane's q (S^T col)
#pragma unroll
    for (int kt = 0; kt < 4; kt++) {
      const int kbase = k0 + kt * 16;
      unsigned short* pdst = &Pw[l15 * 68 + kt * 16 + quad * 4];
      if (kt * 16 <= krel) {
        if (kbase + 15 > qw) {                  // boundary subtile: mask
#pragma unroll
          for (int r = 0; r < 4; r++)
            if (kbase + quad * 4 + r > qrow) sa[kt][r] = -INFINITY;
        }
        const float p0 = EXP2F(sa[kt][0]), p1 = EXP2F(sa[kt][1]);
        const float p2 = EXP2F(sa[kt][2]), p3 = EXP2F(sa[kt][3]);
        l_part += (p0 + p1) + (p2 + p3);
        uint2 pk; pk.x = pack2bf(p0, p1); pk.y = pack2bf(p2, p3);
        *(uint2*)pdst = pk;
      } else if ((kt >> 1) * 32 <= krel) {      // zero-fill rest of read half
        uint2 z; z.x = 0u; z.y = 0u;
        *(uint2*)pdst = z;
      }
    }
    asm volatile("s_waitcnt lgkmcnt(0)" ::: "memory");  // P writes (wave-local)

    // O^T += V^T P^T : A = Vt frag (swizzled LDS), B = P frag (b64 reads)
#pragma unroll
    for (int ks = 0; ks < 2; ks++) {
      if (ks * 32 > krel) break;
      const unsigned short* ps = &Pw[l15 * 68 + ks * 32 + quad * 8];
      union { ushort4v h[2]; bf16x8 v; } pu;
      pu.h[0] = *(const ushort4v*)ps;
      pu.h[1] = *(const ushort4v*)(ps + 4);
#pragma unroll
      for (int mt = 0; mt < 4; mt++) {
        const bf16x8 vf = *(const bf16x8*)(&Vsb[(mt * 16 + l15) * 64] + (ks ? sw1 : sw0));
        O[mt] = __builtin_amdgcn_mfma_f32_16x16x32_bf16(vf, pu.v, O[mt], 0, 0, 0);
      }
    }
  }

  // l: reduce partial sums across the 4 quads (keys were split across quads)
#pragma unroll
  for (int d = 16; d < 64; d <<= 1)
    l_part += __shfl_xor(l_part, d, 64);

  // epilogue: O^T (hd=row, q=col) -> Pw [q][hd] stride 68 -> coalesced CTX
  {
    const float inv = 1.0f / l_part;
#pragma unroll
    for (int mt = 0; mt < 4; mt++)
#pragma unroll
      for (int a = 0; a < 2; a++) {
        const unsigned int pk =
            (unsigned int)f2bf(O[mt][2 * a] * inv) |
            ((unsigned int)f2bf(O[mt][2 * a + 1] * inv) << 16);
        *(unsigned int*)&Pw[l15 * 68 + mt * 16 + quad * 4 + 2 * a] = pk;
      }
  }
  asm volatile("s_waitcnt lgkmcnt(0)" ::: "memory");
  const int b = bh >> 4, h = bh & 15;
#pragma unroll
  for (int it = 0; it < 2; it++) {
    const int g = it * 64 + lane;
    const int row = g >> 3, c8 = (g & 7) * 8;
    union { ushort4v h[2]; ushort8v v; } ou;
    ou.h[0] = *(const ushort4v*)&Pw[row * 68 + c8];
    ou.h[1] = *(const ushort4v*)&Pw[row * 68 + c8 + 4];
    const int s = qw + row;
    *(ushort8v*)&CTX[((size_t)(b * S_LEN + s)) * KD + h * HDIM + c8] = ou.v;
  }
}

// ---------------------------------------------------------------------------
// Kernel 4: output projection ctx[8192,1024] x W_o[1024,1024]^T + b_o -> fp32
// R7 async-pipelined K-loop (double buffer, distance-1).
// ---------------------------------------------------------------------------
__global__ __launch_bounds__(256) void gemm_out(
    const unsigned short* __restrict__ A,
    const unsigned short* __restrict__ Bw,
    const float* __restrict__ bias,
    float* __restrict__ out)
{
  __shared__ unsigned short smem[16384];   // buf0 As|Bs, buf1 As|Bs
  const int tid  = threadIdx.x;
  const int wave = tid >> 6, lane = tid & 63;
  const int quad = lane >> 4, l15 = lane & 15;
  const int wr = wave >> 1, wc = wave & 1;
  const int m0 = blockIdx.x * 128, n0 = blockIdx.y * 128;

  const int srow = lane >> 2;
  const int scol = ((lane & 3) ^ ((srow >> 1) & 3)) * 8;
  const unsigned short* gA = A  + (size_t)(m0 + wave * 32 + srow) * KD + scol;
  const unsigned short* gB = Bw + (size_t)(n0 + wave * 32 + srow) * KD + scol;

  const floatx4 fzero = {0.f, 0.f, 0.f, 0.f};
  floatx4 acc[4][4];
#pragma unroll
  for (int i = 0; i < 4; i++)
#pragma unroll
    for (int j = 0; j < 4; j++) acc[i][j] = fzero;

  {
    unsigned short* lA = smem + wave * 1024;
    unsigned short* lB = smem + 4096 + wave * 1024;
    async_cp16(gA,                    lA);
    async_cp16(gA + (size_t)16 * KD,  lA + 512);
    async_cp16(gB,                    lB);
    async_cp16(gB + (size_t)16 * KD,  lB + 512);
  }
  const int lsw = (l15 >> 1) & 3;

#pragma unroll 2
  for (int it = 0; it < 32; it++) {
    asm volatile("s_waitcnt vmcnt(0) lgkmcnt(0)\n\ts_barrier" ::: "memory");
    if (it + 1 < 32) {
      const int nb = (it + 1) & 1;
      const int ko = (it + 1) * 32;
      unsigned short* lA = smem + nb * 8192 + wave * 1024;
      unsigned short* lB = smem + nb * 8192 + 4096 + wave * 1024;
      async_cp16(gA + ko,                   lA);
      async_cp16(gA + ko + (size_t)16 * KD, lA + 512);
      async_cp16(gB + ko,                   lB);
      async_cp16(gB + ko + (size_t)16 * KD, lB + 512);
    }
    const unsigned short* As = smem + (it & 1) * 8192;
    const unsigned short* Bs = As + 4096;

    bf16x8 af[4], bfrag[4];
#pragma unroll
    for (int i = 0; i < 4; i++)
      af[i] = *(const bf16x8*)&As[(wr * 64 + i * 16 + l15) * 32 + (quad ^ lsw) * 8];
#pragma unroll
    for (int j = 0; j < 4; j++)
      bfrag[j] = *(const bf16x8*)&Bs[(wc * 64 + j * 16 + l15) * 32 + (quad ^ lsw) * 8];
#pragma unroll
    for (int i = 0; i < 4; i++)
#pragma unroll
      for (int j = 0; j < 4; j++)
        acc[i][j] = __builtin_amdgcn_mfma_f32_16x16x32_bf16(af[i], bfrag[j], acc[i][j], 0, 0, 0);
  }

#pragma unroll
  for (int j = 0; j < 4; j++) {
    const int n = n0 + wc * 64 + j * 16 + l15;
    const float bb = bias[n];
#pragma unroll
    for (int i = 0; i < 4; i++) {
#pragma unroll
      for (int r = 0; r < 4; r++) {
        const int m = m0 + wr * 64 + i * 16 + quad * 4 + r;
        out[(size_t)m * KD + n] = acc[i][j][r] + bb;
      }
    }
  }
}

// ---------------------------------------------------------------------------
extern "C" void kernel_launch(void* const* d_in, const int* in_sizes, int n_in,
                              void* d_out, int out_size, void* d_ws, size_t ws_size,
                              hipStream_t stream) {
  (void)in_sizes; (void)n_in; (void)out_size;
  const float* x  = (const float*)d_in[0];
  const float* wq = (const float*)d_in[1];
  const float* wk = (const float*)d_in[2];
  const float* wv = (const float*)d_in[3];
  const float* wo = (const float*)d_in[4];
  const float* bo = (const float*)d_in[5];
  float* out = (float*)d_out;

  if (ws_size < (size_t)92274688) return;
  char* ws = (char*)d_ws;
  unsigned short* xb    = (unsigned short*)(ws);
  unsigned short* wqkvb = (unsigned short*)(ws + (size_t)16777216);
  unsigned short* wob   = (unsigned short*)(ws + (size_t)23068672);
  unsigned short* qws   = (unsigned short*)(ws + (size_t)25165824);
  unsigned short* kws   = (unsigned short*)(ws + (size_t)41943040);
  unsigned short* vtws  = (unsigned short*)(ws + (size_t)58720256);
  unsigned short* ctxws = (unsigned short*)(ws + (size_t)75497472);

  cvt_kernel<<<12288, 256, 0, stream>>>(x, wq, wk, wv, wo, xb, wqkvb, wob);
  gemm_qkv<<<dim3(64, 24), 256, 0, stream>>>(xb, wqkvb, qws, kws, vtws);
  attn_kernel<<<dim3(64, 16), 512, 0, stream>>>(qws, kws, vtws, ctxws);
  gemm_out<<<dim3(64, 8), 256, 0, stream>>>(ctxws, wob, bo, out);
}